// Round 1
// baseline (1744.369 us; speedup 1.0000x reference)
//
#include <hip/hip_runtime.h>

#define NN 100000
#define NE 1600000
// dims: IN=128, EDGE=32, HID=256, OUT=128

typedef __attribute__((ext_vector_type(8))) short short8;
typedef __attribute__((ext_vector_type(4))) float f32x4;

__device__ __forceinline__ unsigned short f2bf(float f) {
  unsigned u = __float_as_uint(f);
  u = (u + 0x7FFFu + ((u >> 16) & 1u)) >> 16;
  return (unsigned short)u;
}

__device__ __forceinline__ float gelu_exact(float v) {
  return 0.5f * v * (1.0f + erff(v * 0.70710678118654752f));
}

// Pack [K][N] fp32 weights into fragment-ordered bf16 for the B operand of
// mfma_f32_16x16x32_bf16: dst[((kt*NT+nt)*64 + l)*8 + j] = W[kt*32+(l>>4)*8+j][nt*16+(l&15)]
__global__ void pack_b_kernel(const float* __restrict__ src,
                              unsigned short* __restrict__ dst,
                              int N, int NT, int total) {
  int tid = blockIdx.x * blockDim.x + threadIdx.x;
  if (tid >= total) return;
  int j = tid & 7;
  int l = (tid >> 3) & 63;
  int f = tid >> 9;
  int nt = f % NT;
  int kt = f / NT;
  int k = kt * 32 + (l >> 4) * 8 + j;
  int n = nt * 16 + (l & 15);
  dst[tid] = f2bf(src[k * N + n]);
}

#define SA1 168   // LDS row stride (bf16) for 160-wide A1 tile, 16B-aligned rows
#define SA2 264   // LDS row stride (bf16) for 256-wide A2/A3 tiles

// Fused edge-message kernel: gather -> GEMM1(K=160) -> LN -> GELU -> GEMM2(K=256) -> atomic scatter
__global__ __launch_bounds__(256) void edge_kernel(
    const float* __restrict__ x, const int* __restrict__ ei,
    const float* __restrict__ ea, const unsigned short* __restrict__ W1F,
    const float* __restrict__ b1, const float* __restrict__ g1,
    const float* __restrict__ be1, const unsigned short* __restrict__ W2F,
    const float* __restrict__ b2, float* __restrict__ agg) {
  __shared__ unsigned short A1[64][SA1];
  __shared__ unsigned short A2[64][SA2];
  __shared__ float lnsum[4][64];
  __shared__ float lnsq[4][64];
  __shared__ int rowidx[64];
  __shared__ int colidx[64];

  int tid = threadIdx.x;
  int e0 = blockIdx.x * 64;
  if (tid < 64) {
    rowidx[tid] = ei[e0 + tid];
    colidx[tid] = ei[NE + e0 + tid];
  }
  __syncthreads();

  // Stage A1: 64 edges x 160 bf16  (128 gathered from x[row], 32 from edge_attr)
#pragma unroll
  for (int i = 0; i < 10; ++i) {
    int g = i * 256 + tid;            // [0, 2560) = 64 edges * 40 float4-groups
    int e = g / 40;
    int c4 = g - e * 40;
    float4 v;
    if (c4 < 32)
      v = *(const float4*)(x + (size_t)rowidx[e] * 128 + c4 * 4);
    else
      v = *(const float4*)(ea + (size_t)(e0 + e) * 32 + (c4 - 32) * 4);
    ushort4 b;
    b.x = f2bf(v.x); b.y = f2bf(v.y); b.z = f2bf(v.z); b.w = f2bf(v.w);
    *(ushort4*)(&A1[e][c4 * 4]) = b;
  }
  __syncthreads();

  int w = tid >> 6;        // wave id 0..3 -> owns 64 cols of HID in GEMM1, 32 cols of OUT in GEMM2
  int l = tid & 63;
  int lr = l & 15;         // row/col within 16-tile
  int lg = l >> 4;         // k-group / row-group

  // ---- GEMM1: h[64 x 256] = A1[64 x 160] @ W1[160 x 256]
  f32x4 acc[4][4];
#pragma unroll
  for (int r = 0; r < 4; ++r)
#pragma unroll
    for (int c = 0; c < 4; ++c) acc[r][c] = {0.f, 0.f, 0.f, 0.f};

#pragma unroll
  for (int kt = 0; kt < 5; ++kt) {
    short8 af[4];
#pragma unroll
    for (int r = 0; r < 4; ++r)
      af[r] = *(const short8*)(&A1[r * 16 + lr][kt * 32 + lg * 8]);
#pragma unroll
    for (int c = 0; c < 4; ++c) {
      int nt = w * 4 + c;
      short8 bfr = *(const short8*)(W1F + (size_t)(((kt * 16 + nt) * 64 + l) * 8));
#pragma unroll
      for (int r = 0; r < 4; ++r)
        acc[r][c] = __builtin_amdgcn_mfma_f32_16x16x32_bf16(af[r], bfr, acc[r][c], 0, 0, 0);
    }
  }

  // ---- epilogue 1: +b1, LayerNorm over 256 cols (cross-wave), exact GELU, write bf16 A2
  float b1v[4], g1v[4], bev[4];
#pragma unroll
  for (int c = 0; c < 4; ++c) {
    int col = w * 64 + c * 16 + lr;
    b1v[c] = b1[col]; g1v[c] = g1[col]; bev[c] = be1[col];
  }
  float s1[4][4], s2[4][4];
#pragma unroll
  for (int r = 0; r < 4; ++r)
#pragma unroll
    for (int q = 0; q < 4; ++q) {
      float t = 0.f, t2 = 0.f;
#pragma unroll
      for (int c = 0; c < 4; ++c) {
        float v = acc[r][c][q] + b1v[c];
        acc[r][c][q] = v;
        t += v; t2 += v * v;
      }
      s1[r][q] = t; s2[r][q] = t2;
    }
#pragma unroll
  for (int m = 1; m <= 8; m <<= 1)
#pragma unroll
    for (int r = 0; r < 4; ++r)
#pragma unroll
      for (int q = 0; q < 4; ++q) {
        s1[r][q] += __shfl_xor(s1[r][q], m, 64);
        s2[r][q] += __shfl_xor(s2[r][q], m, 64);
      }
  if (lr == 0) {
#pragma unroll
    for (int r = 0; r < 4; ++r)
#pragma unroll
      for (int q = 0; q < 4; ++q) {
        int row = r * 16 + lg * 4 + q;
        lnsum[w][row] = s1[r][q];
        lnsq[w][row] = s2[r][q];
      }
  }
  __syncthreads();
#pragma unroll
  for (int r = 0; r < 4; ++r)
#pragma unroll
    for (int q = 0; q < 4; ++q) {
      int row = r * 16 + lg * 4 + q;
      float tot = lnsum[0][row] + lnsum[1][row] + lnsum[2][row] + lnsum[3][row];
      float tot2 = lnsq[0][row] + lnsq[1][row] + lnsq[2][row] + lnsq[3][row];
      float mu = tot * (1.0f / 256.0f);
      float var = tot2 * (1.0f / 256.0f) - mu * mu;
      float rstd = rsqrtf(var + 1e-5f);
#pragma unroll
      for (int c = 0; c < 4; ++c) {
        float v = (acc[r][c][q] - mu) * rstd * g1v[c] + bev[c];
        v = gelu_exact(v);
        A2[row][w * 64 + c * 16 + lr] = f2bf(v);
      }
    }
  __syncthreads();

  // ---- GEMM2: msg[64 x 128] = A2[64 x 256] @ W2[256 x 128]
  f32x4 acc2[4][2];
#pragma unroll
  for (int r = 0; r < 4; ++r)
#pragma unroll
    for (int c = 0; c < 2; ++c) acc2[r][c] = {0.f, 0.f, 0.f, 0.f};

#pragma unroll
  for (int kt = 0; kt < 8; ++kt) {
    short8 af[4];
#pragma unroll
    for (int r = 0; r < 4; ++r)
      af[r] = *(const short8*)(&A2[r * 16 + lr][kt * 32 + lg * 8]);
#pragma unroll
    for (int c2 = 0; c2 < 2; ++c2) {
      int nt = w * 2 + c2;
      short8 bfr = *(const short8*)(W2F + (size_t)(((kt * 8 + nt) * 64 + l) * 8));
#pragma unroll
      for (int r = 0; r < 4; ++r)
        acc2[r][c2] = __builtin_amdgcn_mfma_f32_16x16x32_bf16(af[r], bfr, acc2[r][c2], 0, 0, 0);
    }
  }

  // ---- epilogue 2: +b2, atomic scatter-add into agg[col_node]
  float b2v[2];
#pragma unroll
  for (int c2 = 0; c2 < 2; ++c2) b2v[c2] = b2[w * 32 + c2 * 16 + lr];
#pragma unroll
  for (int r = 0; r < 4; ++r)
#pragma unroll
    for (int q = 0; q < 4; ++q) {
      int eloc = r * 16 + lg * 4 + q;
      int node = colidx[eloc];
#pragma unroll
      for (int c2 = 0; c2 < 2; ++c2) {
        unsafeAtomicAdd(agg + (size_t)node * 128 + w * 32 + c2 * 16 + lr,
                        acc2[r][c2][q] + b2v[c2]);
      }
    }
}

// Node update: u = gelu(LN(concat(x, agg) @ Wu + bu)) + x
__global__ __launch_bounds__(256) void node_kernel(
    const float* __restrict__ x, const float* __restrict__ agg,
    const unsigned short* __restrict__ WuF, const float* __restrict__ bu,
    const float* __restrict__ gu, const float* __restrict__ beu,
    float* __restrict__ out) {
  __shared__ unsigned short A3[64][SA2];
  __shared__ float lnsum[4][64];
  __shared__ float lnsq[4][64];

  int tid = threadIdx.x;
  int n0 = blockIdx.x * 64;

  // Stage A3: 64 nodes x 256 bf16 = [x | agg]
#pragma unroll
  for (int i = 0; i < 16; ++i) {
    int g = i * 256 + tid;          // [0, 4096) = 64 rows * 64 float4-groups
    int e = g >> 6;
    int c4 = g & 63;
    int node = n0 + e;
    float4 v = make_float4(0.f, 0.f, 0.f, 0.f);
    if (node < NN) {
      if (c4 < 32)
        v = *(const float4*)(x + (size_t)node * 128 + c4 * 4);
      else
        v = *(const float4*)(agg + (size_t)node * 128 + (c4 - 32) * 4);
    }
    ushort4 b;
    b.x = f2bf(v.x); b.y = f2bf(v.y); b.z = f2bf(v.z); b.w = f2bf(v.w);
    *(ushort4*)(&A3[e][c4 * 4]) = b;
  }
  __syncthreads();

  int w = tid >> 6;
  int l = tid & 63;
  int lr = l & 15;
  int lg = l >> 4;

  f32x4 acc[4][2];
#pragma unroll
  for (int r = 0; r < 4; ++r)
#pragma unroll
    for (int c = 0; c < 2; ++c) acc[r][c] = {0.f, 0.f, 0.f, 0.f};

#pragma unroll
  for (int kt = 0; kt < 8; ++kt) {
    short8 af[4];
#pragma unroll
    for (int r = 0; r < 4; ++r)
      af[r] = *(const short8*)(&A3[r * 16 + lr][kt * 32 + lg * 8]);
#pragma unroll
    for (int c2 = 0; c2 < 2; ++c2) {
      int nt = w * 2 + c2;
      short8 bfr = *(const short8*)(WuF + (size_t)(((kt * 8 + nt) * 64 + l) * 8));
#pragma unroll
      for (int r = 0; r < 4; ++r)
        acc[r][c2] = __builtin_amdgcn_mfma_f32_16x16x32_bf16(af[r], bfr, acc[r][c2], 0, 0, 0);
    }
  }

  float buv[2], guv[2], beuv[2];
#pragma unroll
  for (int c2 = 0; c2 < 2; ++c2) {
    int col = w * 32 + c2 * 16 + lr;
    buv[c2] = bu[col]; guv[c2] = gu[col]; beuv[c2] = beu[col];
  }
  float s1[4][4], s2[4][4];
#pragma unroll
  for (int r = 0; r < 4; ++r)
#pragma unroll
    for (int q = 0; q < 4; ++q) {
      float t = 0.f, t2 = 0.f;
#pragma unroll
      for (int c2 = 0; c2 < 2; ++c2) {
        float v = acc[r][c2][q] + buv[c2];
        acc[r][c2][q] = v;
        t += v; t2 += v * v;
      }
      s1[r][q] = t; s2[r][q] = t2;
    }
#pragma unroll
  for (int m = 1; m <= 8; m <<= 1)
#pragma unroll
    for (int r = 0; r < 4; ++r)
#pragma unroll
      for (int q = 0; q < 4; ++q) {
        s1[r][q] += __shfl_xor(s1[r][q], m, 64);
        s2[r][q] += __shfl_xor(s2[r][q], m, 64);
      }
  if (lr == 0) {
#pragma unroll
    for (int r = 0; r < 4; ++r)
#pragma unroll
      for (int q = 0; q < 4; ++q) {
        int row = r * 16 + lg * 4 + q;
        lnsum[w][row] = s1[r][q];
        lnsq[w][row] = s2[r][q];
      }
  }
  __syncthreads();
#pragma unroll
  for (int r = 0; r < 4; ++r)
#pragma unroll
    for (int q = 0; q < 4; ++q) {
      int row = r * 16 + lg * 4 + q;
      int node = n0 + row;
      float tot = lnsum[0][row] + lnsum[1][row] + lnsum[2][row] + lnsum[3][row];
      float tot2 = lnsq[0][row] + lnsq[1][row] + lnsq[2][row] + lnsq[3][row];
      float mu = tot * (1.0f / 128.0f);
      float var = tot2 * (1.0f / 128.0f) - mu * mu;
      float rstd = rsqrtf(var + 1e-5f);
      if (node < NN) {
#pragma unroll
        for (int c2 = 0; c2 < 2; ++c2) {
          int col = w * 32 + c2 * 16 + lr;
          float v = (acc[r][c2][q] - mu) * rstd * guv[c2] + beuv[c2];
          v = gelu_exact(v);
          out[(size_t)node * 128 + col] = v + x[(size_t)node * 128 + col];
        }
      }
    }
}

extern "C" void kernel_launch(void* const* d_in, const int* in_sizes, int n_in,
                              void* d_out, int out_size, void* d_ws, size_t ws_size,
                              hipStream_t stream) {
  const float* x   = (const float*)d_in[0];
  const int*   ei  = (const int*)d_in[1];
  const float* ea  = (const float*)d_in[2];
  const float* W1  = (const float*)d_in[3];
  const float* b1  = (const float*)d_in[4];
  const float* g1  = (const float*)d_in[5];
  const float* be1 = (const float*)d_in[6];
  const float* W2  = (const float*)d_in[7];
  const float* b2  = (const float*)d_in[8];
  const float* Wu  = (const float*)d_in[9];
  const float* bu  = (const float*)d_in[10];
  const float* gu  = (const float*)d_in[11];
  const float* beu = (const float*)d_in[12];
  float* out = (float*)d_out;

  char* ws = (char*)d_ws;
  float* agg = (float*)ws;                                   // NN*128 fp32 = 51.2 MB
  unsigned short* W1F = (unsigned short*)(ws + 51200000);    // 160*256 bf16
  unsigned short* W2F = (unsigned short*)(ws + 51200000 + 81920);
  unsigned short* WuF = (unsigned short*)(ws + 51200000 + 81920 + 65536);

  hipMemsetAsync(agg, 0, (size_t)NN * 128 * sizeof(float), stream);
  pack_b_kernel<<<160, 256, 0, stream>>>(W1, W1F, 256, 16, 160 * 256);
  pack_b_kernel<<<128, 256, 0, stream>>>(W2, W2F, 128, 8, 256 * 128);
  pack_b_kernel<<<128, 256, 0, stream>>>(Wu, WuF, 128, 8, 256 * 128);

  edge_kernel<<<NE / 64, 256, 0, stream>>>(x, ei, ea, W1F, b1, g1, be1, W2F, b2, agg);
  node_kernel<<<(NN + 63) / 64, 256, 0, stream>>>(x, agg, WuF, bu, gu, beu, out);
}